// Round 15
// baseline (85.593 us; speedup 1.0000x reference)
//
#include <hip/hip_runtime.h>
#include <hip/hip_bf16.h>
#include <hip/hip_fp16.h>

typedef __attribute__((ext_vector_type(8))) short short8;
typedef __attribute__((ext_vector_type(4))) short short4v;
typedef __attribute__((ext_vector_type(4))) float f32x4;

#define LQ     2048
#define LK     2048
#define DH     128
#define NB     8
#define KBLK   64
#define SPLITW 512
#define NSMAX  4               /* LK / SPLITW */
#define NQT64  (LQ / 64)       /* 32 q-tiles of 64 rows */

/* ws layout (bytes):
   (unused gap)               @ 0        (4 MB)
   Kbf  [8][2048][128] bf16   @ 4 MB     (4 MB)
   Vt   [8][128][2048] bf16   @ 8 MB     (4 MB)  transposed
   Opart[4][8][2048][128] f16 @ 12 MB    (16 MB) unnormalized per-split O
   Ml   [4][8][2048][2]  f32  @ 76 MB    (0.5 MB) per-split (m, l)          */
#define KBF_OFF (4ull << 20)
#define VT_OFF  (8ull << 20)
#define OP_OFF  (12ull << 20)
#define ML_OFF  (76ull << 20)

static __device__ __forceinline__ unsigned short f2bf(float f) {
  __hip_bfloat16 h = __float2bfloat16(f);
  return __builtin_bit_cast(unsigned short, h);
}
static __device__ __forceinline__ short f2h(float f) {
  __half h = __float2half(f);
  return (short)__builtin_bit_cast(unsigned short, h);
}

#define GLDS16(gp, lp) __builtin_amdgcn_global_load_lds(                    \
    (const __attribute__((address_space(1))) void*)(gp),                    \
    (__attribute__((address_space(3))) void*)(lp), 16, 0, 0)

/* ---- prep: K -> bf16 linear; V -> bf16 transposed; both vlen-gated ---- */
__global__ void __launch_bounds__(256)
prep_kv(const float* __restrict__ Kg, const float* __restrict__ Vg,
        const int* __restrict__ vlens,
        unsigned short* __restrict__ Kbf, unsigned short* __restrict__ Vt) {
  __shared__ unsigned short Lt[64][68]; /* +4 pad breaks bank alignment */
  const int bid = blockIdx.x;
  if (bid < 1024) {
    /* ---- K bf16 convert path: block covers 16 rows of one batch ---- */
    const int b      = bid >> 7;            /* 128 blocks per batch */
    const int row0   = (bid & 127) * 16;    /* first row in batch */
    const int kceil  = (vlens[b] + 63) & ~63;
    if (row0 >= kceil) return;              /* rows never staged */
    int g = bid * 256 + threadIdx.x;
    int off = g * 8;
    float4 a = *(const float4*)(Kg + off);
    float4 c = *(const float4*)(Kg + off + 4);
    short8 v;
    v[0] = (short)f2bf(a.x); v[1] = (short)f2bf(a.y);
    v[2] = (short)f2bf(a.z); v[3] = (short)f2bf(a.w);
    v[4] = (short)f2bf(c.x); v[5] = (short)f2bf(c.y);
    v[6] = (short)f2bf(c.z); v[7] = (short)f2bf(c.w);
    *(short8*)(Kbf + off) = v;
    return;
  }
  /* ---- V transpose path ---- */
  int vb = bid - 1024;           /* 8 b x 32 kt x 2 dt = 512 */
  int dt = vb & 1;
  int kt = (vb >> 1) & 31;
  int b  = vb >> 6;
  if (kt * 64 >= vlens[b]) return;          /* tile never read */
  int t  = threadIdx.x;
  int kr = t >> 2, dc = (t & 3) * 16;
  const float* vp = Vg + (((size_t)b * LK + kt * 64 + kr) * DH + dt * 64 + dc);
#pragma unroll
  for (int j = 0; j < 4; ++j) {
    float4 x = *(const float4*)(vp + j * 4);
    Lt[kr][dc + j * 4 + 0] = f2bf(x.x);
    Lt[kr][dc + j * 4 + 1] = f2bf(x.y);
    Lt[kr][dc + j * 4 + 2] = f2bf(x.z);
    Lt[kr][dc + j * 4 + 3] = f2bf(x.w);
  }
  __syncthreads();
  int dr = t >> 2, kc = (t & 3) * 16;
  short8 w0, w1;
#pragma unroll
  for (int j = 0; j < 8; ++j) w0[j] = (short)Lt[kc + j][dr];
#pragma unroll
  for (int j = 0; j < 8; ++j) w1[j] = (short)Lt[kc + 8 + j][dr];
  unsigned short* op = Vt + (((size_t)b * DH + dt * 64 + dr) * LK + kt * 64 + kc);
  *(short8*)op = w0;
  *(short8*)(op + 8) = w1;
}

/* ---- main: split-K flash attention, 4-wave blocks ----
   r14 structure with ONE change: V is NOT staged to LDS. Every wave read
   the full V tile from LDS anyway (16 KB/wave), so staging saved no read
   volume; V fragments now come straight from L2-resident Vt (r0/r1
   pattern, data-identical). Effects:
   - LDS 72 KB -> 40 KB => 4 blocks/CU (16 waves/CU, was 8): clean
     occupancy test at UNCHANGED tile count/sync structure (r6's confound);
   - per-tile vmcnt drain covers K staging only (4 loads/wave, was 8);
   - 16 V loads/wave/tile pipeline under the dc-loop MFMAs with 2x TLP.
   K staging, softmax, P-bounce, fast path, stores: byte-identical to r14. */
__global__ void __launch_bounds__(256, 4)
attn_split(const float* __restrict__ Qg, const unsigned short* __restrict__ Kbf,
           const unsigned short* __restrict__ Vt, const int* __restrict__ vlens,
           __half* __restrict__ Opart, float* __restrict__ Ml,
           float* __restrict__ Og) {
  const int bid   = blockIdx.x;            /* ((b*4 + split)*32 + qt) */
  const int qt    = bid & (NQT64 - 1);
  const int split = (bid >> 5) & (NSMAX - 1);
  const int b     = bid >> 7;

  const int vlen = vlens[b];
  const int kbeg = split * SPLITW;
  if (kbeg >= vlen) return;                /* dead split */
  const int kend  = min(vlen, kbeg + SPLITW);
  const int ntile = (kend - kbeg + KBLK - 1) / KBLK;

  const int tid  = threadIdx.x;
  const int lane = tid & 63;
  const int w    = tid >> 6;
  const int l15  = lane & 15;
  const int lg   = lane >> 4;

  __shared__ __align__(16) unsigned char Kl[2][16384];
  __shared__ __align__(16) unsigned char Pw[4][2048];

  /* Q fragments: direct f32 read, scale + bf16 convert in-register. */
  const float SCALE = 0.08838834764831845f * 1.4426950408889634f; /* 1/sqrt(128)*log2(e) */
  const int qrow = qt * 64 + w * 16 + l15;
  const float* qpf = Qg + ((size_t)(b * LQ + qrow)) * DH;
  short8 qf[4];
#pragma unroll
  for (int dk = 0; dk < 4; ++dk) {
    float4 x = *(const float4*)(qpf + dk * 32 + lg * 8);
    float4 y = *(const float4*)(qpf + dk * 32 + lg * 8 + 4);
    qf[dk][0] = (short)f2bf(x.x * SCALE); qf[dk][1] = (short)f2bf(x.y * SCALE);
    qf[dk][2] = (short)f2bf(x.z * SCALE); qf[dk][3] = (short)f2bf(x.w * SCALE);
    qf[dk][4] = (short)f2bf(y.x * SCALE); qf[dk][5] = (short)f2bf(y.y * SCALE);
    qf[dk][6] = (short)f2bf(y.z * SCALE); qf[dk][7] = (short)f2bf(y.w * SCALE);
  }

  /* o[dc][r] = O[q = l15][d = dc*16 + lg*4 + r] */
  f32x4 o[8];
#pragma unroll
  for (int i = 0; i < 8; ++i) o[i] = (f32x4){0.f, 0.f, 0.f, 0.f};
  float rm = -1e30f;
  float rl = 0.f;

  const char* Kbase = (const char*)(Kbf + (size_t)b * LK * DH);
  const unsigned short* Vbase = Vt + (size_t)b * DH * LK;

  /* stage K tile t into buffer bsel: each wave stages 4KB (4 x 16B/lane).
     LDS dest linear; global SOURCE pre-swizzled so that a swizzled ds_read
     yields logical data (involution o ^= ((row&7)<<4)).                  */
#define STAGE(t, bsel) do {                                                  \
    const int t0s = kbeg + (t) * KBLK;                                       \
    const char* kg_ = Kbase + (size_t)t0s * (DH * 2);                        \
    _Pragma("unroll")                                                        \
    for (int j = 0; j < 4; ++j) {                                            \
      unsigned ko_ = (unsigned)(w * 4096 + j * 1024 + lane * 16);            \
      unsigned ks_ = ko_ ^ (((ko_ >> 8) & 7u) << 4);                         \
      GLDS16(kg_ + ks_, &Kl[bsel][w * 4096 + j * 1024]);                     \
    }                                                                        \
  } while (0)

  int cur = 0;
  STAGE(0, 0);
  __syncthreads();                         /* drains vmcnt(0) + barrier */

  for (int tt = 0; tt < ntile; ++tt) {
    const int t0 = kbeg + tt * KBLK;
    if (tt + 1 < ntile) STAGE(tt + 1, cur ^ 1);   /* in flight during compute */

    const unsigned char* Kb = Kl[cur];

    /* QK^T swapped: s[ks][r] = S^T[k = t0+ks*16+lg*4+r][q = l15] */
    f32x4 s[4];
#pragma unroll
    for (int ks = 0; ks < 4; ++ks) {
      f32x4 acc = (f32x4){0.f, 0.f, 0.f, 0.f};
      const int krow = ks * 16 + l15;
      const unsigned swzk = ((unsigned)(krow & 7)) << 4;
#pragma unroll
      for (int dk = 0; dk < 4; ++dk) {
        unsigned off = ((unsigned)(krow * 256 + dk * 64 + lg * 16)) ^ swzk;
        short8 kf = *(const short8*)(Kb + off);
        acc = __builtin_amdgcn_mfma_f32_16x16x32_bf16(kf, qf[dk], acc, 0, 0, 0);
      }
      s[ks] = acc;
    }

    /* mask tail keys >= kend */
    if (t0 + KBLK > kend) {
#pragma unroll
      for (int ks = 0; ks < 4; ++ks) {
#pragma unroll
        for (int r = 0; r < 4; ++r) {
          if (t0 + ks * 16 + lg * 4 + r >= kend) s[ks][r] = -1e30f;
        }
      }
    }

    /* online softmax: q lane-local; 2 shfl across lg groups */
    float mk[4];
#pragma unroll
    for (int ks = 0; ks < 4; ++ks)
      mk[ks] = fmaxf(fmaxf(s[ks][0], s[ks][1]), fmaxf(s[ks][2], s[ks][3]));
    float tm = fmaxf(fmaxf(mk[0], mk[1]), fmaxf(mk[2], mk[3]));
    tm = fmaxf(tm, __shfl_xor(tm, 16));
    tm = fmaxf(tm, __shfl_xor(tm, 32));
    float nm = fmaxf(rm, tm);
    float corr = exp2f(rm - nm);
    rm = nm;
#pragma unroll
    for (int ks = 0; ks < 4; ++ks) {
#pragma unroll
      for (int r = 0; r < 4; ++r) s[ks][r] = exp2f(s[ks][r] - nm);
    }

    /* P -> per-wave LDS bounce (bf16, swizzled) */
#pragma unroll
    for (int ks = 0; ks < 4; ++ks) {
      short4v wv;
      wv[0] = (short)f2bf(s[ks][0]); wv[1] = (short)f2bf(s[ks][1]);
      wv[2] = (short)f2bf(s[ks][2]); wv[3] = (short)f2bf(s[ks][3]);
      unsigned off = (unsigned)(l15 * 128 + ks * 32 + lg * 8) ^ ((unsigned)(l15 & 7) << 4);
      *(short4v*)(Pw[w] + off) = wv;
    }

    /* rescale O + row sum while LDS writes drain (corr is lane-local) */
#pragma unroll
    for (int dc = 0; dc < 8; ++dc) o[dc] *= corr;
    float ts = ((s[0][0] + s[0][1]) + (s[0][2] + s[0][3]))
             + ((s[1][0] + s[1][1]) + (s[1][2] + s[1][3]))
             + ((s[2][0] + s[2][1]) + (s[2][2] + s[2][3]))
             + ((s[3][0] + s[3][1]) + (s[3][2] + s[3][3]));
    ts += __shfl_xor(ts, 16);
    ts += __shfl_xor(ts, 32);
    rl = rl * corr + ts;

    /* read P B-fragments */
    short8 pa[2];
#pragma unroll
    for (int kk = 0; kk < 2; ++kk) {
      unsigned off = (unsigned)(l15 * 128 + kk * 64 + lg * 16) ^ ((unsigned)(l15 & 7) << 4);
      pa[kk] = *(const short8*)(Pw[w] + off);
    }

    /* PV swapped: o[dc] += Vt-frag (A, row=d, direct from L2-resident Vt)
       x P-frag (B, col=q). 16 independent 16B loads pipeline under MFMAs. */
#pragma unroll
    for (int dc = 0; dc < 8; ++dc) {
      const unsigned short* vp = Vbase + ((size_t)(dc * 16 + l15)) * LK + t0 + lg * 8;
#pragma unroll
      for (int kk = 0; kk < 2; ++kk) {
        short8 vf = *(const short8*)(vp + kk * 32);
        o[dc] = __builtin_amdgcn_mfma_f32_16x16x32_bf16(vf, pa[kk], o[dc], 0, 0, 0);
      }
    }

    __syncthreads();                       /* drain K staging vmcnt + swap */
    cur ^= 1;
  }

  if (vlen <= SPLITW) {
    /* single live split: normalize in-kernel, write final output directly */
    float inv = 1.0f / rl;
    float* og0 = Og + ((size_t)(b * LQ + qrow)) * DH;
#pragma unroll
    for (int dc = 0; dc < 8; ++dc) {
      f32x4 v = o[dc] * inv;
      *(f32x4*)(og0 + dc * 16 + lg * 4) = v;
    }
    return;
  }

  /* store unnormalized partials as fp16 (4 halves = 8B per store) + (m, l) */
  __half* op0 = Opart + ((size_t)(split * NB + b) * LQ + qt * 64 + w * 16) * DH;
#pragma unroll
  for (int dc = 0; dc < 8; ++dc) {
    short4v hv;
    hv[0] = f2h(o[dc][0]); hv[1] = f2h(o[dc][1]);
    hv[2] = f2h(o[dc][2]); hv[3] = f2h(o[dc][3]);
    *(short4v*)(op0 + (size_t)l15 * DH + dc * 16 + lg * 4) = hv;
  }
  if (lane < 16) {
    size_t ro = (size_t)(split * NB + b) * LQ + qt * 64 + w * 16 + lane;
    float2 ml;
    ml.x = rm;
    ml.y = rl;
    *(float2*)(Ml + ro * 2) = ml;
  }
#undef STAGE
}

/* ---- combine: merge 2..4 split partials per row, vectorized ----
   16 rows per 256-thr block: 16 threads x 8 d-elements each row ->
   16B f16 loads. Rows of single-split batches were written directly
   by attn_split and are skipped here.                                    */
__global__ void __launch_bounds__(256)
attn_combine(const __half* __restrict__ Opart, const float* __restrict__ Ml,
             const int* __restrict__ vlens, float* __restrict__ Og) {
  const int t   = threadIdx.x;
  const int gq  = blockIdx.x * 16 + (t >> 4);   /* global row 0..16383 */
  const int b   = gq >> 11;
  const int q   = gq & (LQ - 1);
  const int d0  = (t & 15) * 8;
  const int vlen = vlens[b];
  if (vlen <= SPLITW) return;                   /* Og written by attn_split */
  const int nlive = (vlen + SPLITW - 1) / SPLITW;
  float m = -1e30f;
  for (int s = 0; s < nlive; ++s)
    m = fmaxf(m, Ml[((size_t)(s * NB + b) * LQ + q) * 2]);
  float L = 0.f;
  float acc[8] = {0.f, 0.f, 0.f, 0.f, 0.f, 0.f, 0.f, 0.f};
  for (int s = 0; s < nlive; ++s) {
    size_t ro = (size_t)(s * NB + b) * LQ + q;
    float2 ml = *(const float2*)(Ml + ro * 2);
    float wgt = exp2f(ml.x - m);
    L += wgt * ml.y;
    const __half* op = Opart + ro * DH + d0;
    short4v h0 = *(const short4v*)(op);
    short4v h1 = *(const short4v*)(op + 4);
#pragma unroll
    for (int j = 0; j < 4; ++j) {
      acc[j]     += wgt * __half2float(__builtin_bit_cast(__half, (unsigned short)h0[j]));
      acc[4 + j] += wgt * __half2float(__builtin_bit_cast(__half, (unsigned short)h1[j]));
    }
  }
  float invL = 1.0f / L;
  float* og = Og + ((size_t)b * LQ + q) * DH + d0;
  f32x4 v0, v1;
#pragma unroll
  for (int j = 0; j < 4; ++j) { v0[j] = acc[j] * invL; v1[j] = acc[4 + j] * invL; }
  *(f32x4*)(og) = v0;
  *(f32x4*)(og + 4) = v1;
}

extern "C" void kernel_launch(void* const* d_in, const int* in_sizes, int n_in,
                              void* d_out, int out_size, void* d_ws, size_t ws_size,
                              hipStream_t stream) {
  const float* Q  = (const float*)d_in[0];
  const float* K  = (const float*)d_in[1];
  const float* V  = (const float*)d_in[2];
  const int*   vl = (const int*)d_in[3];
  float* O = (float*)d_out;

  unsigned short* Kbf = (unsigned short*)((char*)d_ws + KBF_OFF);
  unsigned short* Vt  = (unsigned short*)((char*)d_ws + VT_OFF);
  __half* Opart = (__half*)((char*)d_ws + OP_OFF);
  float* Ml     = (float*)((char*)d_ws + ML_OFF);

  hipLaunchKernelGGL(prep_kv, dim3(1536), dim3(256), 0, stream, K, V, vl, Kbf, Vt);
  hipLaunchKernelGGL(attn_split, dim3(NB * NSMAX * NQT64), dim3(256), 0, stream,
                     Q, Kbf, Vt, vl, Opart, Ml, O);
  hipLaunchKernelGGL(attn_combine, dim3(NB * LQ / 16), dim3(256), 0, stream,
                     Opart, Ml, vl, O);
}

// Round 16
// 85.364 us; speedup vs baseline: 1.0027x; 1.0027x over previous
//
#include <hip/hip_runtime.h>
#include <hip/hip_bf16.h>
#include <hip/hip_fp16.h>

typedef __attribute__((ext_vector_type(8))) short short8;
typedef __attribute__((ext_vector_type(4))) short short4v;
typedef __attribute__((ext_vector_type(4))) float f32x4;

#define LQ     2048
#define LK     2048
#define DH     128
#define NB     8
#define KBLK   64
#define SPLITW 512
#define NSMAX  4               /* LK / SPLITW */
#define NQT64  (LQ / 64)       /* 32 q-tiles of 64 rows */

/* ws layout (bytes):
   (unused gap)               @ 0        (4 MB)
   Kbf  [8][2048][128] bf16   @ 4 MB     (4 MB)
   Vt   [8][128][2048] bf16   @ 8 MB     (4 MB)  transposed
   Opart[4][8][2048][128] f16 @ 12 MB    (16 MB) unnormalized per-split O
   Ml   [4][8][2048][2]  f32  @ 76 MB    (0.5 MB) per-split (m, l)          */
#define KBF_OFF (4ull << 20)
#define VT_OFF  (8ull << 20)
#define OP_OFF  (12ull << 20)
#define ML_OFF  (76ull << 20)

static __device__ __forceinline__ unsigned short f2bf(float f) {
  __hip_bfloat16 h = __float2bfloat16(f);
  return __builtin_bit_cast(unsigned short, h);
}
static __device__ __forceinline__ short f2h(float f) {
  __half h = __float2half(f);
  return (short)__builtin_bit_cast(unsigned short, h);
}

#define GLDS16(gp, lp) __builtin_amdgcn_global_load_lds(                    \
    (const __attribute__((address_space(1))) void*)(gp),                    \
    (__attribute__((address_space(3))) void*)(lp), 16, 0, 0)

/* ---- prep: K -> bf16 linear; V -> bf16 transposed; both vlen-gated ---- */
__global__ void __launch_bounds__(256)
prep_kv(const float* __restrict__ Kg, const float* __restrict__ Vg,
        const int* __restrict__ vlens,
        unsigned short* __restrict__ Kbf, unsigned short* __restrict__ Vt) {
  __shared__ unsigned short Lt[64][68]; /* +4 pad breaks bank alignment */
  const int bid = blockIdx.x;
  if (bid < 1024) {
    /* ---- K bf16 convert path: block covers 16 rows of one batch ---- */
    const int b      = bid >> 7;            /* 128 blocks per batch */
    const int row0   = (bid & 127) * 16;    /* first row in batch */
    const int kceil  = (vlens[b] + 63) & ~63;
    if (row0 >= kceil) return;              /* rows never staged */
    int g = bid * 256 + threadIdx.x;
    int off = g * 8;
    float4 a = *(const float4*)(Kg + off);
    float4 c = *(const float4*)(Kg + off + 4);
    short8 v;
    v[0] = (short)f2bf(a.x); v[1] = (short)f2bf(a.y);
    v[2] = (short)f2bf(a.z); v[3] = (short)f2bf(a.w);
    v[4] = (short)f2bf(c.x); v[5] = (short)f2bf(c.y);
    v[6] = (short)f2bf(c.z); v[7] = (short)f2bf(c.w);
    *(short8*)(Kbf + off) = v;
    return;
  }
  /* ---- V transpose path ---- */
  int vb = bid - 1024;           /* 8 b x 32 kt x 2 dt = 512 */
  int dt = vb & 1;
  int kt = (vb >> 1) & 31;
  int b  = vb >> 6;
  if (kt * 64 >= vlens[b]) return;          /* tile never read */
  int t  = threadIdx.x;
  int kr = t >> 2, dc = (t & 3) * 16;
  const float* vp = Vg + (((size_t)b * LK + kt * 64 + kr) * DH + dt * 64 + dc);
#pragma unroll
  for (int j = 0; j < 4; ++j) {
    float4 x = *(const float4*)(vp + j * 4);
    Lt[kr][dc + j * 4 + 0] = f2bf(x.x);
    Lt[kr][dc + j * 4 + 1] = f2bf(x.y);
    Lt[kr][dc + j * 4 + 2] = f2bf(x.z);
    Lt[kr][dc + j * 4 + 3] = f2bf(x.w);
  }
  __syncthreads();
  int dr = t >> 2, kc = (t & 3) * 16;
  short8 w0, w1;
#pragma unroll
  for (int j = 0; j < 8; ++j) w0[j] = (short)Lt[kc + j][dr];
#pragma unroll
  for (int j = 0; j < 8; ++j) w1[j] = (short)Lt[kc + 8 + j][dr];
  unsigned short* op = Vt + (((size_t)b * DH + dt * 64 + dr) * LK + kt * 64 + kc);
  *(short8*)op = w0;
  *(short8*)(op + 8) = w1;
}

/* ---- main: split-K flash attention, 4-wave blocks ----
   r15 body (V-direct: V fragments read straight from L2-resident Vt, no V
   staging -> LDS 40 KB) with the SPILL FIXED: __launch_bounds__(256,3).
   r15's (256,4) forced a 128-VGPR cap the body can't meet -> allocator
   crushed to 64 VGPR + scratch spill (72us). (256,3) caps at ~168 VGPR,
   well above the ~110 natural need -> no spill, and LDS 3x40=120KB allows
   3 blocks/CU co-resident (12 waves/CU, +50% vs r14's 8). This is the
   clean occupancy test r6 (tile-count confound) and r15 (spill) missed.
   K staging, softmax, P-bounce, fast path, stores: byte-identical to r14. */
__global__ void __launch_bounds__(256, 3)
attn_split(const float* __restrict__ Qg, const unsigned short* __restrict__ Kbf,
           const unsigned short* __restrict__ Vt, const int* __restrict__ vlens,
           __half* __restrict__ Opart, float* __restrict__ Ml,
           float* __restrict__ Og) {
  const int bid   = blockIdx.x;            /* ((b*4 + split)*32 + qt) */
  const int qt    = bid & (NQT64 - 1);
  const int split = (bid >> 5) & (NSMAX - 1);
  const int b     = bid >> 7;

  const int vlen = vlens[b];
  const int kbeg = split * SPLITW;
  if (kbeg >= vlen) return;                /* dead split */
  const int kend  = min(vlen, kbeg + SPLITW);
  const int ntile = (kend - kbeg + KBLK - 1) / KBLK;

  const int tid  = threadIdx.x;
  const int lane = tid & 63;
  const int w    = tid >> 6;
  const int l15  = lane & 15;
  const int lg   = lane >> 4;

  __shared__ __align__(16) unsigned char Kl[2][16384];
  __shared__ __align__(16) unsigned char Pw[4][2048];

  /* Q fragments: direct f32 read, scale + bf16 convert in-register. */
  const float SCALE = 0.08838834764831845f * 1.4426950408889634f; /* 1/sqrt(128)*log2(e) */
  const int qrow = qt * 64 + w * 16 + l15;
  const float* qpf = Qg + ((size_t)(b * LQ + qrow)) * DH;
  short8 qf[4];
#pragma unroll
  for (int dk = 0; dk < 4; ++dk) {
    float4 x = *(const float4*)(qpf + dk * 32 + lg * 8);
    float4 y = *(const float4*)(qpf + dk * 32 + lg * 8 + 4);
    qf[dk][0] = (short)f2bf(x.x * SCALE); qf[dk][1] = (short)f2bf(x.y * SCALE);
    qf[dk][2] = (short)f2bf(x.z * SCALE); qf[dk][3] = (short)f2bf(x.w * SCALE);
    qf[dk][4] = (short)f2bf(y.x * SCALE); qf[dk][5] = (short)f2bf(y.y * SCALE);
    qf[dk][6] = (short)f2bf(y.z * SCALE); qf[dk][7] = (short)f2bf(y.w * SCALE);
  }

  /* o[dc][r] = O[q = l15][d = dc*16 + lg*4 + r] */
  f32x4 o[8];
#pragma unroll
  for (int i = 0; i < 8; ++i) o[i] = (f32x4){0.f, 0.f, 0.f, 0.f};
  float rm = -1e30f;
  float rl = 0.f;

  const char* Kbase = (const char*)(Kbf + (size_t)b * LK * DH);
  const unsigned short* Vbase = Vt + (size_t)b * DH * LK;

  /* stage K tile t into buffer bsel: each wave stages 4KB (4 x 16B/lane).
     LDS dest linear; global SOURCE pre-swizzled so that a swizzled ds_read
     yields logical data (involution o ^= ((row&7)<<4)).                  */
#define STAGE(t, bsel) do {                                                  \
    const int t0s = kbeg + (t) * KBLK;                                       \
    const char* kg_ = Kbase + (size_t)t0s * (DH * 2);                        \
    _Pragma("unroll")                                                        \
    for (int j = 0; j < 4; ++j) {                                            \
      unsigned ko_ = (unsigned)(w * 4096 + j * 1024 + lane * 16);            \
      unsigned ks_ = ko_ ^ (((ko_ >> 8) & 7u) << 4);                         \
      GLDS16(kg_ + ks_, &Kl[bsel][w * 4096 + j * 1024]);                     \
    }                                                                        \
  } while (0)

  int cur = 0;
  STAGE(0, 0);
  __syncthreads();                         /* drains vmcnt(0) + barrier */

  for (int tt = 0; tt < ntile; ++tt) {
    const int t0 = kbeg + tt * KBLK;
    if (tt + 1 < ntile) STAGE(tt + 1, cur ^ 1);   /* in flight during compute */

    const unsigned char* Kb = Kl[cur];

    /* QK^T swapped: s[ks][r] = S^T[k = t0+ks*16+lg*4+r][q = l15] */
    f32x4 s[4];
#pragma unroll
    for (int ks = 0; ks < 4; ++ks) {
      f32x4 acc = (f32x4){0.f, 0.f, 0.f, 0.f};
      const int krow = ks * 16 + l15;
      const unsigned swzk = ((unsigned)(krow & 7)) << 4;
#pragma unroll
      for (int dk = 0; dk < 4; ++dk) {
        unsigned off = ((unsigned)(krow * 256 + dk * 64 + lg * 16)) ^ swzk;
        short8 kf = *(const short8*)(Kb + off);
        acc = __builtin_amdgcn_mfma_f32_16x16x32_bf16(kf, qf[dk], acc, 0, 0, 0);
      }
      s[ks] = acc;
    }

    /* mask tail keys >= kend */
    if (t0 + KBLK > kend) {
#pragma unroll
      for (int ks = 0; ks < 4; ++ks) {
#pragma unroll
        for (int r = 0; r < 4; ++r) {
          if (t0 + ks * 16 + lg * 4 + r >= kend) s[ks][r] = -1e30f;
        }
      }
    }

    /* online softmax: q lane-local; 2 shfl across lg groups */
    float mk[4];
#pragma unroll
    for (int ks = 0; ks < 4; ++ks)
      mk[ks] = fmaxf(fmaxf(s[ks][0], s[ks][1]), fmaxf(s[ks][2], s[ks][3]));
    float tm = fmaxf(fmaxf(mk[0], mk[1]), fmaxf(mk[2], mk[3]));
    tm = fmaxf(tm, __shfl_xor(tm, 16));
    tm = fmaxf(tm, __shfl_xor(tm, 32));
    float nm = fmaxf(rm, tm);
    float corr = exp2f(rm - nm);
    rm = nm;
#pragma unroll
    for (int ks = 0; ks < 4; ++ks) {
#pragma unroll
      for (int r = 0; r < 4; ++r) s[ks][r] = exp2f(s[ks][r] - nm);
    }

    /* P -> per-wave LDS bounce (bf16, swizzled) */
#pragma unroll
    for (int ks = 0; ks < 4; ++ks) {
      short4v wv;
      wv[0] = (short)f2bf(s[ks][0]); wv[1] = (short)f2bf(s[ks][1]);
      wv[2] = (short)f2bf(s[ks][2]); wv[3] = (short)f2bf(s[ks][3]);
      unsigned off = (unsigned)(l15 * 128 + ks * 32 + lg * 8) ^ ((unsigned)(l15 & 7) << 4);
      *(short4v*)(Pw[w] + off) = wv;
    }

    /* rescale O + row sum while LDS writes drain (corr is lane-local) */
#pragma unroll
    for (int dc = 0; dc < 8; ++dc) o[dc] *= corr;
    float ts = ((s[0][0] + s[0][1]) + (s[0][2] + s[0][3]))
             + ((s[1][0] + s[1][1]) + (s[1][2] + s[1][3]))
             + ((s[2][0] + s[2][1]) + (s[2][2] + s[2][3]))
             + ((s[3][0] + s[3][1]) + (s[3][2] + s[3][3]));
    ts += __shfl_xor(ts, 16);
    ts += __shfl_xor(ts, 32);
    rl = rl * corr + ts;

    /* read P B-fragments */
    short8 pa[2];
#pragma unroll
    for (int kk = 0; kk < 2; ++kk) {
      unsigned off = (unsigned)(l15 * 128 + kk * 64 + lg * 16) ^ ((unsigned)(l15 & 7) << 4);
      pa[kk] = *(const short8*)(Pw[w] + off);
    }

    /* PV swapped: o[dc] += Vt-frag (A, row=d, direct from L2-resident Vt)
       x P-frag (B, col=q). 16 independent 16B loads pipeline under MFMAs. */
#pragma unroll
    for (int dc = 0; dc < 8; ++dc) {
      const unsigned short* vp = Vbase + ((size_t)(dc * 16 + l15)) * LK + t0 + lg * 8;
#pragma unroll
      for (int kk = 0; kk < 2; ++kk) {
        short8 vf = *(const short8*)(vp + kk * 32);
        o[dc] = __builtin_amdgcn_mfma_f32_16x16x32_bf16(vf, pa[kk], o[dc], 0, 0, 0);
      }
    }

    __syncthreads();                       /* drain K staging vmcnt + swap */
    cur ^= 1;
  }

  if (vlen <= SPLITW) {
    /* single live split: normalize in-kernel, write final output directly */
    float inv = 1.0f / rl;
    float* og0 = Og + ((size_t)(b * LQ + qrow)) * DH;
#pragma unroll
    for (int dc = 0; dc < 8; ++dc) {
      f32x4 v = o[dc] * inv;
      *(f32x4*)(og0 + dc * 16 + lg * 4) = v;
    }
    return;
  }

  /* store unnormalized partials as fp16 (4 halves = 8B per store) + (m, l) */
  __half* op0 = Opart + ((size_t)(split * NB + b) * LQ + qt * 64 + w * 16) * DH;
#pragma unroll
  for (int dc = 0; dc < 8; ++dc) {
    short4v hv;
    hv[0] = f2h(o[dc][0]); hv[1] = f2h(o[dc][1]);
    hv[2] = f2h(o[dc][2]); hv[3] = f2h(o[dc][3]);
    *(short4v*)(op0 + (size_t)l15 * DH + dc * 16 + lg * 4) = hv;
  }
  if (lane < 16) {
    size_t ro = (size_t)(split * NB + b) * LQ + qt * 64 + w * 16 + lane;
    float2 ml;
    ml.x = rm;
    ml.y = rl;
    *(float2*)(Ml + ro * 2) = ml;
  }
#undef STAGE
}

/* ---- combine: merge 2..4 split partials per row, vectorized ----
   16 rows per 256-thr block: 16 threads x 8 d-elements each row ->
   16B f16 loads. Rows of single-split batches were written directly
   by attn_split and are skipped here.                                    */
__global__ void __launch_bounds__(256)
attn_combine(const __half* __restrict__ Opart, const float* __restrict__ Ml,
             const int* __restrict__ vlens, float* __restrict__ Og) {
  const int t   = threadIdx.x;
  const int gq  = blockIdx.x * 16 + (t >> 4);   /* global row 0..16383 */
  const int b   = gq >> 11;
  const int q   = gq & (LQ - 1);
  const int d0  = (t & 15) * 8;
  const int vlen = vlens[b];
  if (vlen <= SPLITW) return;                   /* Og written by attn_split */
  const int nlive = (vlen + SPLITW - 1) / SPLITW;
  float m = -1e30f;
  for (int s = 0; s < nlive; ++s)
    m = fmaxf(m, Ml[((size_t)(s * NB + b) * LQ + q) * 2]);
  float L = 0.f;
  float acc[8] = {0.f, 0.f, 0.f, 0.f, 0.f, 0.f, 0.f, 0.f};
  for (int s = 0; s < nlive; ++s) {
    size_t ro = (size_t)(s * NB + b) * LQ + q;
    float2 ml = *(const float2*)(Ml + ro * 2);
    float wgt = exp2f(ml.x - m);
    L += wgt * ml.y;
    const __half* op = Opart + ro * DH + d0;
    short4v h0 = *(const short4v*)(op);
    short4v h1 = *(const short4v*)(op + 4);
#pragma unroll
    for (int j = 0; j < 4; ++j) {
      acc[j]     += wgt * __half2float(__builtin_bit_cast(__half, (unsigned short)h0[j]));
      acc[4 + j] += wgt * __half2float(__builtin_bit_cast(__half, (unsigned short)h1[j]));
    }
  }
  float invL = 1.0f / L;
  float* og = Og + ((size_t)b * LQ + q) * DH + d0;
  f32x4 v0, v1;
#pragma unroll
  for (int j = 0; j < 4; ++j) { v0[j] = acc[j] * invL; v1[j] = acc[4 + j] * invL; }
  *(f32x4*)(og) = v0;
  *(f32x4*)(og + 4) = v1;
}

extern "C" void kernel_launch(void* const* d_in, const int* in_sizes, int n_in,
                              void* d_out, int out_size, void* d_ws, size_t ws_size,
                              hipStream_t stream) {
  const float* Q  = (const float*)d_in[0];
  const float* K  = (const float*)d_in[1];
  const float* V  = (const float*)d_in[2];
  const int*   vl = (const int*)d_in[3];
  float* O = (float*)d_out;

  unsigned short* Kbf = (unsigned short*)((char*)d_ws + KBF_OFF);
  unsigned short* Vt  = (unsigned short*)((char*)d_ws + VT_OFF);
  __half* Opart = (__half*)((char*)d_ws + OP_OFF);
  float* Ml     = (float*)((char*)d_ws + ML_OFF);

  hipLaunchKernelGGL(prep_kv, dim3(1536), dim3(256), 0, stream, K, V, vl, Kbf, Vt);
  hipLaunchKernelGGL(attn_split, dim3(NB * NSMAX * NQT64), dim3(256), 0, stream,
                     Q, Kbf, Vt, vl, Opart, Ml, O);
  hipLaunchKernelGGL(attn_combine, dim3(NB * LQ / 16), dim3(256), 0, stream,
                     Opart, Ml, vl, O);
}

// Round 17
// 44.920 us; speedup vs baseline: 1.9054x; 1.9004x over previous
//
#include <hip/hip_runtime.h>
#include <hip/hip_bf16.h>
#include <hip/hip_fp16.h>

typedef __attribute__((ext_vector_type(8))) short short8;
typedef __attribute__((ext_vector_type(4))) short short4v;
typedef __attribute__((ext_vector_type(4))) float f32x4;

#define LQ     2048
#define LK     2048
#define DH     128
#define NB     8
#define KBLK   64
#define SPLITW 512
#define NSMAX  4               /* LK / SPLITW */
#define NQT64  (LQ / 64)       /* 32 q-tiles of 64 rows */

/* ws layout (bytes):
   (unused gap)               @ 0        (4 MB)
   Kbf  [8][2048][128] bf16   @ 4 MB     (4 MB)
   Vt   [8][128][2048] bf16   @ 8 MB     (4 MB)  transposed
   Opart[4][8][2048][128] f16 @ 12 MB    (16 MB) unnormalized per-split O
   Ml   [4][8][2048][2]  f32  @ 76 MB    (0.5 MB) per-split (m, l)          */
#define KBF_OFF (4ull << 20)
#define VT_OFF  (8ull << 20)
#define OP_OFF  (12ull << 20)
#define ML_OFF  (76ull << 20)

static __device__ __forceinline__ unsigned short f2bf(float f) {
  __hip_bfloat16 h = __float2bfloat16(f);
  return __builtin_bit_cast(unsigned short, h);
}
static __device__ __forceinline__ short f2h(float f) {
  __half h = __float2half(f);
  return (short)__builtin_bit_cast(unsigned short, h);
}

#define GLDS16(gp, lp) __builtin_amdgcn_global_load_lds(                    \
    (const __attribute__((address_space(1))) void*)(gp),                    \
    (__attribute__((address_space(3))) void*)(lp), 16, 0, 0)

/* ---- prep: K -> bf16 linear; V -> bf16 transposed; both vlen-gated ---- */
__global__ void __launch_bounds__(256)
prep_kv(const float* __restrict__ Kg, const float* __restrict__ Vg,
        const int* __restrict__ vlens,
        unsigned short* __restrict__ Kbf, unsigned short* __restrict__ Vt) {
  __shared__ unsigned short Lt[64][68]; /* +4 pad breaks bank alignment */
  const int bid = blockIdx.x;
  if (bid < 1024) {
    /* ---- K bf16 convert path: block covers 16 rows of one batch ---- */
    const int b      = bid >> 7;            /* 128 blocks per batch */
    const int row0   = (bid & 127) * 16;    /* first row in batch */
    const int kceil  = (vlens[b] + 63) & ~63;
    if (row0 >= kceil) return;              /* rows never staged */
    int g = bid * 256 + threadIdx.x;
    int off = g * 8;
    float4 a = *(const float4*)(Kg + off);
    float4 c = *(const float4*)(Kg + off + 4);
    short8 v;
    v[0] = (short)f2bf(a.x); v[1] = (short)f2bf(a.y);
    v[2] = (short)f2bf(a.z); v[3] = (short)f2bf(a.w);
    v[4] = (short)f2bf(c.x); v[5] = (short)f2bf(c.y);
    v[6] = (short)f2bf(c.z); v[7] = (short)f2bf(c.w);
    *(short8*)(Kbf + off) = v;
    return;
  }
  /* ---- V transpose path ---- */
  int vb = bid - 1024;           /* 8 b x 32 kt x 2 dt = 512 */
  int dt = vb & 1;
  int kt = (vb >> 1) & 31;
  int b  = vb >> 6;
  if (kt * 64 >= vlens[b]) return;          /* tile never staged */
  int t  = threadIdx.x;
  int kr = t >> 2, dc = (t & 3) * 16;
  const float* vp = Vg + (((size_t)b * LK + kt * 64 + kr) * DH + dt * 64 + dc);
#pragma unroll
  for (int j = 0; j < 4; ++j) {
    float4 x = *(const float4*)(vp + j * 4);
    Lt[kr][dc + j * 4 + 0] = f2bf(x.x);
    Lt[kr][dc + j * 4 + 1] = f2bf(x.y);
    Lt[kr][dc + j * 4 + 2] = f2bf(x.z);
    Lt[kr][dc + j * 4 + 3] = f2bf(x.w);
  }
  __syncthreads();
  int dr = t >> 2, kc = (t & 3) * 16;
  short8 w0, w1;
#pragma unroll
  for (int j = 0; j < 8; ++j) w0[j] = (short)Lt[kc + j][dr];
#pragma unroll
  for (int j = 0; j < 8; ++j) w1[j] = (short)Lt[kc + 8 + j][dr];
  unsigned short* op = Vt + (((size_t)b * DH + dt * 64 + dr) * LK + kt * 64 + kc);
  *(short8*)op = w0;
  *(short8*)(op + 8) = w1;
}

/* ---- main: split-K flash attention, 4-wave blocks, async LDS staging ----
   The session's proven best (r14, 44.8us): KBLK=64, 4 waves x 16 q-rows,
   SPLITW=512, qt-low decode, K[64][128]+Vt[128][64] bf16 double-buffered
   via global_load_lds (XOR-swizzled source, linear dest — rule #21),
   stage(t+1) at loop top, __syncthreads drains, direct f32 Q read,
   fp16 partials, single-split fast path writes Og directly.
   NOTE (r15/r16 lesson): do NOT read V direct from global in the PV loop —
   the backend then allocates only 64 arch VGPRs (payload moved to AGPRs)
   and serializes the 16 in-flight V loads (~72us). V must be LDS-staged.
   Do NOT raise the launch_bounds min-occupancy: (256,2) is the proven cap. */
__global__ void __launch_bounds__(256, 2)
attn_split(const float* __restrict__ Qg, const unsigned short* __restrict__ Kbf,
           const unsigned short* __restrict__ Vt, const int* __restrict__ vlens,
           __half* __restrict__ Opart, float* __restrict__ Ml,
           float* __restrict__ Og) {
  const int bid   = blockIdx.x;            /* ((b*4 + split)*32 + qt) */
  const int qt    = bid & (NQT64 - 1);
  const int split = (bid >> 5) & (NSMAX - 1);
  const int b     = bid >> 7;

  const int vlen = vlens[b];
  const int kbeg = split * SPLITW;
  if (kbeg >= vlen) return;                /* dead split */
  const int kend  = min(vlen, kbeg + SPLITW);
  const int ntile = (kend - kbeg + KBLK - 1) / KBLK;

  const int tid  = threadIdx.x;
  const int lane = tid & 63;
  const int w    = tid >> 6;
  const int l15  = lane & 15;
  const int lg   = lane >> 4;

  __shared__ __align__(16) unsigned char Kl[2][16384];
  __shared__ __align__(16) unsigned char Vl[2][16384];
  __shared__ __align__(16) unsigned char Pw[4][2048];

  /* Q fragments: direct f32 read, scale + bf16 convert in-register. */
  const float SCALE = 0.08838834764831845f * 1.4426950408889634f; /* 1/sqrt(128)*log2(e) */
  const int qrow = qt * 64 + w * 16 + l15;
  const float* qpf = Qg + ((size_t)(b * LQ + qrow)) * DH;
  short8 qf[4];
#pragma unroll
  for (int dk = 0; dk < 4; ++dk) {
    float4 x = *(const float4*)(qpf + dk * 32 + lg * 8);
    float4 y = *(const float4*)(qpf + dk * 32 + lg * 8 + 4);
    qf[dk][0] = (short)f2bf(x.x * SCALE); qf[dk][1] = (short)f2bf(x.y * SCALE);
    qf[dk][2] = (short)f2bf(x.z * SCALE); qf[dk][3] = (short)f2bf(x.w * SCALE);
    qf[dk][4] = (short)f2bf(y.x * SCALE); qf[dk][5] = (short)f2bf(y.y * SCALE);
    qf[dk][6] = (short)f2bf(y.z * SCALE); qf[dk][7] = (short)f2bf(y.w * SCALE);
  }

  /* o[dc][r] = O[q = l15][d = dc*16 + lg*4 + r] */
  f32x4 o[8];
#pragma unroll
  for (int i = 0; i < 8; ++i) o[i] = (f32x4){0.f, 0.f, 0.f, 0.f};
  float rm = -1e30f;
  float rl = 0.f;

  const char* Kbase = (const char*)(Kbf + (size_t)b * LK * DH);
  const char* Vbase = (const char*)(Vt + (size_t)b * DH * LK);

  /* stage tile t into buffer bsel: each wave stages 4KB of K + 4KB of V.
     LDS dest linear; global SOURCE pre-swizzled so that a swizzled ds_read
     yields logical data (involution o ^= ((row&7)<<4)).                  */
#define STAGE(t, bsel) do {                                                  \
    const int t0s = kbeg + (t) * KBLK;                                       \
    const char* kg_ = Kbase + (size_t)t0s * (DH * 2);                        \
    _Pragma("unroll")                                                        \
    for (int j = 0; j < 4; ++j) {                                            \
      unsigned ko_ = (unsigned)(w * 4096 + j * 1024 + lane * 16);            \
      unsigned ks_ = ko_ ^ (((ko_ >> 8) & 7u) << 4);                         \
      GLDS16(kg_ + ks_, &Kl[bsel][w * 4096 + j * 1024]);                     \
    }                                                                        \
    _Pragma("unroll")                                                        \
    for (int j = 0; j < 4; ++j) {                                            \
      unsigned vo_ = (unsigned)(w * 4096 + j * 1024 + lane * 16);            \
      unsigned d_  = vo_ >> 7;                                               \
      unsigned vs_ = (vo_ & 127u) ^ ((d_ & 7u) << 4);                        \
      const char* vg_ = Vbase + ((size_t)d_ * LK + t0s) * 2 + vs_;           \
      GLDS16(vg_, &Vl[bsel][w * 4096 + j * 1024]);                           \
    }                                                                        \
  } while (0)

  int cur = 0;
  STAGE(0, 0);
  __syncthreads();                         /* drains vmcnt(0) + barrier */

  for (int tt = 0; tt < ntile; ++tt) {
    const int t0 = kbeg + tt * KBLK;
    if (tt + 1 < ntile) STAGE(tt + 1, cur ^ 1);   /* in flight during compute */

    const unsigned char* Kb = Kl[cur];
    const unsigned char* Vb = Vl[cur];

    /* QK^T swapped: s[ks][r] = S^T[k = t0+ks*16+lg*4+r][q = l15] */
    f32x4 s[4];
#pragma unroll
    for (int ks = 0; ks < 4; ++ks) {
      f32x4 acc = (f32x4){0.f, 0.f, 0.f, 0.f};
      const int krow = ks * 16 + l15;
      const unsigned swzk = ((unsigned)(krow & 7)) << 4;
#pragma unroll
      for (int dk = 0; dk < 4; ++dk) {
        unsigned off = ((unsigned)(krow * 256 + dk * 64 + lg * 16)) ^ swzk;
        short8 kf = *(const short8*)(Kb + off);
        acc = __builtin_amdgcn_mfma_f32_16x16x32_bf16(kf, qf[dk], acc, 0, 0, 0);
      }
      s[ks] = acc;
    }

    /* mask tail keys >= kend */
    if (t0 + KBLK > kend) {
#pragma unroll
      for (int ks = 0; ks < 4; ++ks) {
#pragma unroll
        for (int r = 0; r < 4; ++r) {
          if (t0 + ks * 16 + lg * 4 + r >= kend) s[ks][r] = -1e30f;
        }
      }
    }

    /* online softmax: q lane-local; 2 shfl across lg groups */
    float mk[4];
#pragma unroll
    for (int ks = 0; ks < 4; ++ks)
      mk[ks] = fmaxf(fmaxf(s[ks][0], s[ks][1]), fmaxf(s[ks][2], s[ks][3]));
    float tm = fmaxf(fmaxf(mk[0], mk[1]), fmaxf(mk[2], mk[3]));
    tm = fmaxf(tm, __shfl_xor(tm, 16));
    tm = fmaxf(tm, __shfl_xor(tm, 32));
    float nm = fmaxf(rm, tm);
    float corr = exp2f(rm - nm);
    rm = nm;
#pragma unroll
    for (int ks = 0; ks < 4; ++ks) {
#pragma unroll
      for (int r = 0; r < 4; ++r) s[ks][r] = exp2f(s[ks][r] - nm);
    }

    /* P -> per-wave LDS bounce (bf16, swizzled) */
#pragma unroll
    for (int ks = 0; ks < 4; ++ks) {
      short4v wv;
      wv[0] = (short)f2bf(s[ks][0]); wv[1] = (short)f2bf(s[ks][1]);
      wv[2] = (short)f2bf(s[ks][2]); wv[3] = (short)f2bf(s[ks][3]);
      unsigned off = (unsigned)(l15 * 128 + ks * 32 + lg * 8) ^ ((unsigned)(l15 & 7) << 4);
      *(short4v*)(Pw[w] + off) = wv;
    }

    /* rescale O + row sum while LDS writes drain (corr is lane-local) */
#pragma unroll
    for (int dc = 0; dc < 8; ++dc) o[dc] *= corr;
    float ts = ((s[0][0] + s[0][1]) + (s[0][2] + s[0][3]))
             + ((s[1][0] + s[1][1]) + (s[1][2] + s[1][3]))
             + ((s[2][0] + s[2][1]) + (s[2][2] + s[2][3]))
             + ((s[3][0] + s[3][1]) + (s[3][2] + s[3][3]));
    ts += __shfl_xor(ts, 16);
    ts += __shfl_xor(ts, 32);
    rl = rl * corr + ts;

    /* read P B-fragments */
    short8 pa[2];
#pragma unroll
    for (int kk = 0; kk < 2; ++kk) {
      unsigned off = (unsigned)(l15 * 128 + kk * 64 + lg * 16) ^ ((unsigned)(l15 & 7) << 4);
      pa[kk] = *(const short8*)(Pw[w] + off);
    }

    /* PV swapped: o[dc] += Vt-frag (A, row=d) x P-frag (B, col=q) */
#pragma unroll
    for (int dc = 0; dc < 8; ++dc) {
      const int d = dc * 16 + l15;
      const unsigned swzv = ((unsigned)(d & 7)) << 4;
#pragma unroll
      for (int kk = 0; kk < 2; ++kk) {
        unsigned off = ((unsigned)(d * 128 + kk * 64 + lg * 16)) ^ swzv;
        short8 vf = *(const short8*)(Vb + off);
        o[dc] = __builtin_amdgcn_mfma_f32_16x16x32_bf16(vf, pa[kk], o[dc], 0, 0, 0);
      }
    }

    __syncthreads();                       /* drain staging vmcnt + swap */
    cur ^= 1;
  }

  if (vlen <= SPLITW) {
    /* single live split: normalize in-kernel, write final output directly */
    float inv = 1.0f / rl;
    float* og0 = Og + ((size_t)(b * LQ + qrow)) * DH;
#pragma unroll
    for (int dc = 0; dc < 8; ++dc) {
      f32x4 v = o[dc] * inv;
      *(f32x4*)(og0 + dc * 16 + lg * 4) = v;
    }
    return;
  }

  /* store unnormalized partials as fp16 (4 halves = 8B per store) + (m, l) */
  __half* op0 = Opart + ((size_t)(split * NB + b) * LQ + qt * 64 + w * 16) * DH;
#pragma unroll
  for (int dc = 0; dc < 8; ++dc) {
    short4v hv;
    hv[0] = f2h(o[dc][0]); hv[1] = f2h(o[dc][1]);
    hv[2] = f2h(o[dc][2]); hv[3] = f2h(o[dc][3]);
    *(short4v*)(op0 + (size_t)l15 * DH + dc * 16 + lg * 4) = hv;
  }
  if (lane < 16) {
    size_t ro = (size_t)(split * NB + b) * LQ + qt * 64 + w * 16 + lane;
    float2 ml;
    ml.x = rm;
    ml.y = rl;
    *(float2*)(Ml + ro * 2) = ml;
  }
#undef STAGE
}

/* ---- combine: merge 2..4 split partials per row, vectorized ----
   16 rows per 256-thr block: 16 threads x 8 d-elements each row ->
   16B f16 loads. Rows of single-split batches were written directly
   by attn_split and are skipped here.                                    */
__global__ void __launch_bounds__(256)
attn_combine(const __half* __restrict__ Opart, const float* __restrict__ Ml,
             const int* __restrict__ vlens, float* __restrict__ Og) {
  const int t   = threadIdx.x;
  const int gq  = blockIdx.x * 16 + (t >> 4);   /* global row 0..16383 */
  const int b   = gq >> 11;
  const int q   = gq & (LQ - 1);
  const int d0  = (t & 15) * 8;
  const int vlen = vlens[b];
  if (vlen <= SPLITW) return;                   /* Og written by attn_split */
  const int nlive = (vlen + SPLITW - 1) / SPLITW;
  float m = -1e30f;
  for (int s = 0; s < nlive; ++s)
    m = fmaxf(m, Ml[((size_t)(s * NB + b) * LQ + q) * 2]);
  float L = 0.f;
  float acc[8] = {0.f, 0.f, 0.f, 0.f, 0.f, 0.f, 0.f, 0.f};
  for (int s = 0; s < nlive; ++s) {
    size_t ro = (size_t)(s * NB + b) * LQ + q;
    float2 ml = *(const float2*)(Ml + ro * 2);
    float wgt = exp2f(ml.x - m);
    L += wgt * ml.y;
    const __half* op = Opart + ro * DH + d0;
    short4v h0 = *(const short4v*)(op);
    short4v h1 = *(const short4v*)(op + 4);
#pragma unroll
    for (int j = 0; j < 4; ++j) {
      acc[j]     += wgt * __half2float(__builtin_bit_cast(__half, (unsigned short)h0[j]));
      acc[4 + j] += wgt * __half2float(__builtin_bit_cast(__half, (unsigned short)h1[j]));
    }
  }
  float invL = 1.0f / L;
  float* og = Og + ((size_t)b * LQ + q) * DH + d0;
  f32x4 v0, v1;
#pragma unroll
  for (int j = 0; j < 4; ++j) { v0[j] = acc[j] * invL; v1[j] = acc[4 + j] * invL; }
  *(f32x4*)(og) = v0;
  *(f32x4*)(og + 4) = v1;
}

extern "C" void kernel_launch(void* const* d_in, const int* in_sizes, int n_in,
                              void* d_out, int out_size, void* d_ws, size_t ws_size,
                              hipStream_t stream) {
  const float* Q  = (const float*)d_in[0];
  const float* K  = (const float*)d_in[1];
  const float* V  = (const float*)d_in[2];
  const int*   vl = (const int*)d_in[3];
  float* O = (float*)d_out;

  unsigned short* Kbf = (unsigned short*)((char*)d_ws + KBF_OFF);
  unsigned short* Vt  = (unsigned short*)((char*)d_ws + VT_OFF);
  __half* Opart = (__half*)((char*)d_ws + OP_OFF);
  float* Ml     = (float*)((char*)d_ws + ML_OFF);

  hipLaunchKernelGGL(prep_kv, dim3(1536), dim3(256), 0, stream, K, V, vl, Kbf, Vt);
  hipLaunchKernelGGL(attn_split, dim3(NB * NSMAX * NQT64), dim3(256), 0, stream,
                     Q, Kbf, Vt, vl, Opart, Ml, O);
  hipLaunchKernelGGL(attn_combine, dim3(NB * LQ / 16), dim3(256), 0, stream,
                     Opart, Ml, vl, O);
}

// Round 18
// 44.235 us; speedup vs baseline: 1.9350x; 1.0155x over previous
//
#include <hip/hip_runtime.h>
#include <hip/hip_bf16.h>
#include <hip/hip_fp16.h>

typedef __attribute__((ext_vector_type(8))) short short8;
typedef __attribute__((ext_vector_type(4))) short short4v;
typedef __attribute__((ext_vector_type(4))) float f32x4;

#define LQ     2048
#define LK     2048
#define DH     128
#define NB     8
#define KBLK   64
#define SPLITW 512
#define NSMAX  4               /* LK / SPLITW */
#define NQT64  (LQ / 64)       /* 32 q-tiles of 64 rows */

/* ws layout (bytes):
   (unused gap)               @ 0        (4 MB)
   Kbf  [8][2048][128] bf16   @ 4 MB     (4 MB)
   Vt   [8][128][2048] bf16   @ 8 MB     (4 MB)  transposed
   Opart[4][8][2048][128] f16 @ 12 MB    (16 MB) unnormalized per-split O
   Ml   [4][8][2048][2]  f32  @ 76 MB    (0.5 MB) per-split (m, l)          */
#define KBF_OFF (4ull << 20)
#define VT_OFF  (8ull << 20)
#define OP_OFF  (12ull << 20)
#define ML_OFF  (76ull << 20)

static __device__ __forceinline__ unsigned short f2bf(float f) {
  __hip_bfloat16 h = __float2bfloat16(f);
  return __builtin_bit_cast(unsigned short, h);
}
static __device__ __forceinline__ short f2h(float f) {
  __half h = __float2half(f);
  return (short)__builtin_bit_cast(unsigned short, h);
}

#define GLDS16(gp, lp) __builtin_amdgcn_global_load_lds(                    \
    (const __attribute__((address_space(1))) void*)(gp),                    \
    (__attribute__((address_space(3))) void*)(lp), 16, 0, 0)

/* ---- prep: K -> bf16 linear; V -> bf16 transposed; both vlen-gated ---- */
__global__ void __launch_bounds__(256)
prep_kv(const float* __restrict__ Kg, const float* __restrict__ Vg,
        const int* __restrict__ vlens,
        unsigned short* __restrict__ Kbf, unsigned short* __restrict__ Vt) {
  __shared__ unsigned short Lt[64][68]; /* +4 pad breaks bank alignment */
  const int bid = blockIdx.x;
  if (bid < 1024) {
    /* ---- K bf16 convert path: block covers 16 rows of one batch ---- */
    const int b      = bid >> 7;            /* 128 blocks per batch */
    const int row0   = (bid & 127) * 16;    /* first row in batch */
    const int kceil  = (vlens[b] + 63) & ~63;
    if (row0 >= kceil) return;              /* rows never staged */
    int g = bid * 256 + threadIdx.x;
    int off = g * 8;
    float4 a = *(const float4*)(Kg + off);
    float4 c = *(const float4*)(Kg + off + 4);
    short8 v;
    v[0] = (short)f2bf(a.x); v[1] = (short)f2bf(a.y);
    v[2] = (short)f2bf(a.z); v[3] = (short)f2bf(a.w);
    v[4] = (short)f2bf(c.x); v[5] = (short)f2bf(c.y);
    v[6] = (short)f2bf(c.z); v[7] = (short)f2bf(c.w);
    *(short8*)(Kbf + off) = v;
    return;
  }
  /* ---- V transpose path ---- */
  int vb = bid - 1024;           /* 8 b x 32 kt x 2 dt = 512 */
  int dt = vb & 1;
  int kt = (vb >> 1) & 31;
  int b  = vb >> 6;
  if (kt * 64 >= vlens[b]) return;          /* tile never staged */
  int t  = threadIdx.x;
  int kr = t >> 2, dc = (t & 3) * 16;
  const float* vp = Vg + (((size_t)b * LK + kt * 64 + kr) * DH + dt * 64 + dc);
#pragma unroll
  for (int j = 0; j < 4; ++j) {
    float4 x = *(const float4*)(vp + j * 4);
    Lt[kr][dc + j * 4 + 0] = f2bf(x.x);
    Lt[kr][dc + j * 4 + 1] = f2bf(x.y);
    Lt[kr][dc + j * 4 + 2] = f2bf(x.z);
    Lt[kr][dc + j * 4 + 3] = f2bf(x.w);
  }
  __syncthreads();
  int dr = t >> 2, kc = (t & 3) * 16;
  short8 w0, w1;
#pragma unroll
  for (int j = 0; j < 8; ++j) w0[j] = (short)Lt[kc + j][dr];
#pragma unroll
  for (int j = 0; j < 8; ++j) w1[j] = (short)Lt[kc + 8 + j][dr];
  unsigned short* op = Vt + (((size_t)b * DH + dt * 64 + dr) * LK + kt * 64 + kc);
  *(short8*)op = w0;
  *(short8*)(op + 8) = w1;
}

/* ---- main: split-K flash attention, 4-wave blocks ----
   r14 body with ONE change: K/V staging is SINGLE-buffered.
     prologue: STAGE(0); barrier
     iter t:   compute(t) from Kl/Vl;
               if more: barrier (all done reading); STAGE(t+1) into the
               same buffers; barrier (implicit vmcnt(0) drain -> visible)
   LDS 72 KB -> 40 KB => 4 blocks/CU (16 waves/CU, was 8), and all ~640
   live blocks fit ONE dispatch round (1024 slots) — no round-quantized
   tail. Staging latency is now exposed per tile within a block, but in
   this latency-bound regime (all pipes <15%) the 2x resident independent
   blocks more than cover it. This is the clean occupancy test that r6
   (tile-count confound) and r15/r16 (V-direct VGPR pathology — DMA
   staging here carries no VGPR payload) never executed.
   Everything else byte-identical to r14 (proven 44.8us).                  */
__global__ void __launch_bounds__(256, 2)
attn_split(const float* __restrict__ Qg, const unsigned short* __restrict__ Kbf,
           const unsigned short* __restrict__ Vt, const int* __restrict__ vlens,
           __half* __restrict__ Opart, float* __restrict__ Ml,
           float* __restrict__ Og) {
  const int bid   = blockIdx.x;            /* ((b*4 + split)*32 + qt) */
  const int qt    = bid & (NQT64 - 1);
  const int split = (bid >> 5) & (NSMAX - 1);
  const int b     = bid >> 7;

  const int vlen = vlens[b];
  const int kbeg = split * SPLITW;
  if (kbeg >= vlen) return;                /* dead split */
  const int kend  = min(vlen, kbeg + SPLITW);
  const int ntile = (kend - kbeg + KBLK - 1) / KBLK;

  const int tid  = threadIdx.x;
  const int lane = tid & 63;
  const int w    = tid >> 6;
  const int l15  = lane & 15;
  const int lg   = lane >> 4;

  __shared__ __align__(16) unsigned char Kl[16384];
  __shared__ __align__(16) unsigned char Vl[16384];
  __shared__ __align__(16) unsigned char Pw[4][2048];

  /* Q fragments: direct f32 read, scale + bf16 convert in-register. */
  const float SCALE = 0.08838834764831845f * 1.4426950408889634f; /* 1/sqrt(128)*log2(e) */
  const int qrow = qt * 64 + w * 16 + l15;
  const float* qpf = Qg + ((size_t)(b * LQ + qrow)) * DH;
  short8 qf[4];
#pragma unroll
  for (int dk = 0; dk < 4; ++dk) {
    float4 x = *(const float4*)(qpf + dk * 32 + lg * 8);
    float4 y = *(const float4*)(qpf + dk * 32 + lg * 8 + 4);
    qf[dk][0] = (short)f2bf(x.x * SCALE); qf[dk][1] = (short)f2bf(x.y * SCALE);
    qf[dk][2] = (short)f2bf(x.z * SCALE); qf[dk][3] = (short)f2bf(x.w * SCALE);
    qf[dk][4] = (short)f2bf(y.x * SCALE); qf[dk][5] = (short)f2bf(y.y * SCALE);
    qf[dk][6] = (short)f2bf(y.z * SCALE); qf[dk][7] = (short)f2bf(y.w * SCALE);
  }

  /* o[dc][r] = O[q = l15][d = dc*16 + lg*4 + r] */
  f32x4 o[8];
#pragma unroll
  for (int i = 0; i < 8; ++i) o[i] = (f32x4){0.f, 0.f, 0.f, 0.f};
  float rm = -1e30f;
  float rl = 0.f;

  const char* Kbase = (const char*)(Kbf + (size_t)b * LK * DH);
  const char* Vbase = (const char*)(Vt + (size_t)b * DH * LK);

  /* stage tile t: each wave stages 4KB of K + 4KB of V via global_load_lds
     (no VGPR payload). LDS dest linear; global SOURCE pre-swizzled so that
     a swizzled ds_read yields logical data (involution o ^= ((row&7)<<4)). */
#define STAGE(t) do {                                                        \
    const int t0s = kbeg + (t) * KBLK;                                       \
    const char* kg_ = Kbase + (size_t)t0s * (DH * 2);                        \
    _Pragma("unroll")                                                        \
    for (int j = 0; j < 4; ++j) {                                            \
      unsigned ko_ = (unsigned)(w * 4096 + j * 1024 + lane * 16);            \
      unsigned ks_ = ko_ ^ (((ko_ >> 8) & 7u) << 4);                         \
      GLDS16(kg_ + ks_, &Kl[w * 4096 + j * 1024]);                           \
    }                                                                        \
    _Pragma("unroll")                                                        \
    for (int j = 0; j < 4; ++j) {                                            \
      unsigned vo_ = (unsigned)(w * 4096 + j * 1024 + lane * 16);            \
      unsigned d_  = vo_ >> 7;                                               \
      unsigned vs_ = (vo_ & 127u) ^ ((d_ & 7u) << 4);                        \
      const char* vg_ = Vbase + ((size_t)d_ * LK + t0s) * 2 + vs_;           \
      GLDS16(vg_, &Vl[w * 4096 + j * 1024]);                                 \
    }                                                                        \
  } while (0)

  STAGE(0);
  __syncthreads();                         /* drains vmcnt(0) + barrier */

  for (int tt = 0; tt < ntile; ++tt) {
    const int t0 = kbeg + tt * KBLK;

    /* QK^T swapped: s[ks][r] = S^T[k = t0+ks*16+lg*4+r][q = l15] */
    f32x4 s[4];
#pragma unroll
    for (int ks = 0; ks < 4; ++ks) {
      f32x4 acc = (f32x4){0.f, 0.f, 0.f, 0.f};
      const int krow = ks * 16 + l15;
      const unsigned swzk = ((unsigned)(krow & 7)) << 4;
#pragma unroll
      for (int dk = 0; dk < 4; ++dk) {
        unsigned off = ((unsigned)(krow * 256 + dk * 64 + lg * 16)) ^ swzk;
        short8 kf = *(const short8*)(Kl + off);
        acc = __builtin_amdgcn_mfma_f32_16x16x32_bf16(kf, qf[dk], acc, 0, 0, 0);
      }
      s[ks] = acc;
    }

    /* mask tail keys >= kend */
    if (t0 + KBLK > kend) {
#pragma unroll
      for (int ks = 0; ks < 4; ++ks) {
#pragma unroll
        for (int r = 0; r < 4; ++r) {
          if (t0 + ks * 16 + lg * 4 + r >= kend) s[ks][r] = -1e30f;
        }
      }
    }

    /* online softmax: q lane-local; 2 shfl across lg groups */
    float mk[4];
#pragma unroll
    for (int ks = 0; ks < 4; ++ks)
      mk[ks] = fmaxf(fmaxf(s[ks][0], s[ks][1]), fmaxf(s[ks][2], s[ks][3]));
    float tm = fmaxf(fmaxf(mk[0], mk[1]), fmaxf(mk[2], mk[3]));
    tm = fmaxf(tm, __shfl_xor(tm, 16));
    tm = fmaxf(tm, __shfl_xor(tm, 32));
    float nm = fmaxf(rm, tm);
    float corr = exp2f(rm - nm);
    rm = nm;
#pragma unroll
    for (int ks = 0; ks < 4; ++ks) {
#pragma unroll
      for (int r = 0; r < 4; ++r) s[ks][r] = exp2f(s[ks][r] - nm);
    }

    /* P -> per-wave LDS bounce (bf16, swizzled; same-wave ordering) */
#pragma unroll
    for (int ks = 0; ks < 4; ++ks) {
      short4v wv;
      wv[0] = (short)f2bf(s[ks][0]); wv[1] = (short)f2bf(s[ks][1]);
      wv[2] = (short)f2bf(s[ks][2]); wv[3] = (short)f2bf(s[ks][3]);
      unsigned off = (unsigned)(l15 * 128 + ks * 32 + lg * 8) ^ ((unsigned)(l15 & 7) << 4);
      *(short4v*)(Pw[w] + off) = wv;
    }

    /* rescale O + row sum while LDS writes drain (corr is lane-local) */
#pragma unroll
    for (int dc = 0; dc < 8; ++dc) o[dc] *= corr;
    float ts = ((s[0][0] + s[0][1]) + (s[0][2] + s[0][3]))
             + ((s[1][0] + s[1][1]) + (s[1][2] + s[1][3]))
             + ((s[2][0] + s[2][1]) + (s[2][2] + s[2][3]))
             + ((s[3][0] + s[3][1]) + (s[3][2] + s[3][3]));
    ts += __shfl_xor(ts, 16);
    ts += __shfl_xor(ts, 32);
    rl = rl * corr + ts;

    /* read P B-fragments */
    short8 pa[2];
#pragma unroll
    for (int kk = 0; kk < 2; ++kk) {
      unsigned off = (unsigned)(l15 * 128 + kk * 64 + lg * 16) ^ ((unsigned)(l15 & 7) << 4);
      pa[kk] = *(const short8*)(Pw[w] + off);
    }

    /* PV swapped: o[dc] += Vt-frag (A, row=d) x P-frag (B, col=q) */
#pragma unroll
    for (int dc = 0; dc < 8; ++dc) {
      const int d = dc * 16 + l15;
      const unsigned swzv = ((unsigned)(d & 7)) << 4;
#pragma unroll
      for (int kk = 0; kk < 2; ++kk) {
        unsigned off = ((unsigned)(d * 128 + kk * 64 + lg * 16)) ^ swzv;
        short8 vf = *(const short8*)(Vl + off);
        o[dc] = __builtin_amdgcn_mfma_f32_16x16x32_bf16(vf, pa[kk], o[dc], 0, 0, 0);
      }
    }

    /* single-buffer swap: all reads done -> restage -> visible */
    if (tt + 1 < ntile) {
      __syncthreads();                     /* everyone done reading Kl/Vl */
      STAGE(tt + 1);
      __syncthreads();                     /* vmcnt(0) drain + visibility */
    }
  }

  if (vlen <= SPLITW) {
    /* single live split: normalize in-kernel, write final output directly */
    float inv = 1.0f / rl;
    float* og0 = Og + ((size_t)(b * LQ + qrow)) * DH;
#pragma unroll
    for (int dc = 0; dc < 8; ++dc) {
      f32x4 v = o[dc] * inv;
      *(f32x4*)(og0 + dc * 16 + lg * 4) = v;
    }
    return;
  }

  /* store unnormalized partials as fp16 (4 halves = 8B per store) + (m, l) */
  __half* op0 = Opart + ((size_t)(split * NB + b) * LQ + qt * 64 + w * 16) * DH;
#pragma unroll
  for (int dc = 0; dc < 8; ++dc) {
    short4v hv;
    hv[0] = f2h(o[dc][0]); hv[1] = f2h(o[dc][1]);
    hv[2] = f2h(o[dc][2]); hv[3] = f2h(o[dc][3]);
    *(short4v*)(op0 + (size_t)l15 * DH + dc * 16 + lg * 4) = hv;
  }
  if (lane < 16) {
    size_t ro = (size_t)(split * NB + b) * LQ + qt * 64 + w * 16 + lane;
    float2 ml;
    ml.x = rm;
    ml.y = rl;
    *(float2*)(Ml + ro * 2) = ml;
  }
#undef STAGE
}

/* ---- combine: merge 2..4 split partials per row, vectorized ----
   16 rows per 256-thr block: 16 threads x 8 d-elements each row ->
   16B f16 loads. Rows of single-split batches were written directly
   by attn_split and are skipped here.                                    */
__global__ void __launch_bounds__(256)
attn_combine(const __half* __restrict__ Opart, const float* __restrict__ Ml,
             const int* __restrict__ vlens, float* __restrict__ Og) {
  const int t   = threadIdx.x;
  const int gq  = blockIdx.x * 16 + (t >> 4);   /* global row 0..16383 */
  const int b   = gq >> 11;
  const int q   = gq & (LQ - 1);
  const int d0  = (t & 15) * 8;
  const int vlen = vlens[b];
  if (vlen <= SPLITW) return;                   /* Og written by attn_split */
  const int nlive = (vlen + SPLITW - 1) / SPLITW;
  float m = -1e30f;
  for (int s = 0; s < nlive; ++s)
    m = fmaxf(m, Ml[((size_t)(s * NB + b) * LQ + q) * 2]);
  float L = 0.f;
  float acc[8] = {0.f, 0.f, 0.f, 0.f, 0.f, 0.f, 0.f, 0.f};
  for (int s = 0; s < nlive; ++s) {
    size_t ro = (size_t)(s * NB + b) * LQ + q;
    float2 ml = *(const float2*)(Ml + ro * 2);
    float wgt = exp2f(ml.x - m);
    L += wgt * ml.y;
    const __half* op = Opart + ro * DH + d0;
    short4v h0 = *(const short4v*)(op);
    short4v h1 = *(const short4v*)(op + 4);
#pragma unroll
    for (int j = 0; j < 4; ++j) {
      acc[j]     += wgt * __half2float(__builtin_bit_cast(__half, (unsigned short)h0[j]));
      acc[4 + j] += wgt * __half2float(__builtin_bit_cast(__half, (unsigned short)h1[j]));
    }
  }
  float invL = 1.0f / L;
  float* og = Og + ((size_t)b * LQ + q) * DH + d0;
  f32x4 v0, v1;
#pragma unroll
  for (int j = 0; j < 4; ++j) { v0[j] = acc[j] * invL; v1[j] = acc[4 + j] * invL; }
  *(f32x4*)(og) = v0;
  *(f32x4*)(og + 4) = v1;
}

extern "C" void kernel_launch(void* const* d_in, const int* in_sizes, int n_in,
                              void* d_out, int out_size, void* d_ws, size_t ws_size,
                              hipStream_t stream) {
  const float* Q  = (const float*)d_in[0];
  const float* K  = (const float*)d_in[1];
  const float* V  = (const float*)d_in[2];
  const int*   vl = (const int*)d_in[3];
  float* O = (float*)d_out;

  unsigned short* Kbf = (unsigned short*)((char*)d_ws + KBF_OFF);
  unsigned short* Vt  = (unsigned short*)((char*)d_ws + VT_OFF);
  __half* Opart = (__half*)((char*)d_ws + OP_OFF);
  float* Ml     = (float*)((char*)d_ws + ML_OFF);

  hipLaunchKernelGGL(prep_kv, dim3(1536), dim3(256), 0, stream, K, V, vl, Kbf, Vt);
  hipLaunchKernelGGL(attn_split, dim3(NB * NSMAX * NQT64), dim3(256), 0, stream,
                     Q, Kbf, Vt, vl, Opart, Ml, O);
  hipLaunchKernelGGL(attn_combine, dim3(NB * LQ / 16), dim3(256), 0, stream,
                     Opart, Ml, vl, O);
}